// Round 3
// baseline (28455.096 us; speedup 1.0000x reference)
//
#include <hip/hip_runtime.h>
#include <hip/hip_bf16.h>
#include <math.h>

// R3: one row per block, 4 waves K-split each matvec (occupancy 4 waves/SIMD),
// bf16-packed weights in d_ws (u32 = 2 bf16, lane-major) unpacked in-register.
// eps ~= 0 approximation unchanged (passed R1/R2).

#define HD    64
#define TT    128
#define NZN   5
#define ADIM  20

// u32 offsets in d_ws
#define OX   0        // W_x   K=128          : 4096 u32
#define OP1  4096     // Wp1   5 x K=128      : 20480
#define OQ1  24576    // Wq1   5 x K=64       : 10240
#define OP2  34816    // Wp2   5 x K=64       : 10240
#define OQ2  45056    // Wq2   5 x K=64       : 10240
#define OZ   55296    // W_z   K=64           : 2048
#define OIH  57344    // W_ih  K=128 x 3 gates: 12288
#define OHH  69632    // W_hh  K=64  x 3 gates: 6144
// total 75776 u32 = 303 KB

__device__ __forceinline__ float reluf(float x) { return fmaxf(x, 0.f); }
__device__ __forceinline__ float softplusf(float x) {
    return fmaxf(x, 0.f) + log1pf(expf(-fabsf(x)));
}
__device__ __forceinline__ float sigmoidf_(float x) { return 1.f / (1.f + expf(-x)); }

// w = packed bf16 pair (lo = even k, hi = odd k); a = the two fp32 activations
__device__ __forceinline__ float bffma2(unsigned int w, float2 a, float acc) {
    float lo = __uint_as_float(w << 16);
    float hi = __uint_as_float(w & 0xffff0000u);
    acc = fmaf(a.x, lo, acc);
    acc = fmaf(a.y, hi, acc);
    return acc;
}

__device__ __forceinline__ float wave_sum64(float v) {
#pragma unroll
    for (int off = 32; off > 0; off >>= 1) v += __shfl_xor(v, off, 64);
    return v;
}

__device__ __forceinline__ unsigned short f2bf(float x) {
    union { float f; unsigned int u; } v; v.f = x;
    unsigned int r = v.u + 0x7fffu + ((v.u >> 16) & 1u);  // RTNE
    return (unsigned short)(r >> 16);
}
__device__ __forceinline__ unsigned int pkbf(float lo, float hi) {
    return (unsigned int)f2bf(lo) | ((unsigned int)f2bf(hi) << 16);
}

__global__ void vrnn_zero(float* out) { out[22528] = 0.f; }

__global__ __launch_bounds__(256) void vrnn_pack(
    const float* __restrict__ W_x,  const float* __restrict__ Wp1,
    const float* __restrict__ Wq1,  const float* __restrict__ Wp2,
    const float* __restrict__ Wq2,  const float* __restrict__ W_z,
    const float* __restrict__ W_ih, const float* __restrict__ W_hh,
    unsigned int* __restrict__ ws)
{
    const int tid = blockIdx.x * blockDim.x + threadIdx.x;
    const int NT  = gridDim.x * blockDim.x;
    // W_x [128][64]
    for (int e = tid; e < 4096; e += NT) {
        int q = e & 3, ln = (e >> 2) & 63, j = e >> 8;
        int k0 = 8 * j + 2 * q;
        ws[OX + e] = pkbf(W_x[k0 * 64 + ln], W_x[(k0 + 1) * 64 + ln]);
    }
    // Wp1 [5][128][64]
    for (int e = tid; e < 20480; e += NT) {
        int n = e >> 12, r = e & 4095;
        int q = r & 3, ln = (r >> 2) & 63, j = r >> 8;
        int k0 = 8 * j + 2 * q;
        ws[OP1 + e] = pkbf(Wp1[(n * 128 + k0) * 64 + ln], Wp1[(n * 128 + k0 + 1) * 64 + ln]);
    }
    // Wq1 / Wp2 / Wq2 [5][64][64]
    for (int e = tid; e < 10240; e += NT) {
        int n = e >> 11, r = e & 2047;
        int q = r & 3, ln = (r >> 2) & 63, j = r >> 8;
        int k0 = 8 * j + 2 * q;
        ws[OQ1 + e] = pkbf(Wq1[(n * 64 + k0) * 64 + ln], Wq1[(n * 64 + k0 + 1) * 64 + ln]);
        ws[OP2 + e] = pkbf(Wp2[(n * 64 + k0) * 64 + ln], Wp2[(n * 64 + k0 + 1) * 64 + ln]);
        ws[OQ2 + e] = pkbf(Wq2[(n * 64 + k0) * 64 + ln], Wq2[(n * 64 + k0 + 1) * 64 + ln]);
    }
    // W_z [64][64]
    for (int e = tid; e < 2048; e += NT) {
        int q = e & 3, ln = (e >> 2) & 63, j = e >> 8;
        int k0 = 8 * j + 2 * q;
        ws[OZ + e] = pkbf(W_z[k0 * 64 + ln], W_z[(k0 + 1) * 64 + ln]);
    }
    // W_ih [128][192] -> (j,g) blocks
    for (int e = tid; e < 12288; e += NT) {
        int top = e >> 8, r = e & 255;
        int j = top / 3, g = top % 3;
        int q = r & 3, ln = r >> 2;
        int k0 = 8 * j + 2 * q;
        ws[OIH + e] = pkbf(W_ih[k0 * 192 + g * 64 + ln], W_ih[(k0 + 1) * 192 + g * 64 + ln]);
    }
    // W_hh [64][192]
    for (int e = tid; e < 6144; e += NT) {
        int top = e >> 8, r = e & 255;
        int j = top / 3, g = top % 3;
        int q = r & 3, ln = r >> 2;
        int k0 = 8 * j + 2 * q;
        ws[OHH + e] = pkbf(W_hh[k0 * 192 + g * 64 + ln], W_hh[(k0 + 1) * 192 + g * 64 + ln]);
    }
}

__global__ __launch_bounds__(256, 4) void vrnn_main(
    const int* __restrict__ acts, const float* __restrict__ durs,
    const float* __restrict__ W_act, const float* __restrict__ b_act,
    const float* __restrict__ W_dur, const float* __restrict__ b_dur,
    const float* __restrict__ b_x, const float* __restrict__ b_z,
    const float* __restrict__ bp1, const float* __restrict__ bq1,
    const float* __restrict__ bp2, const float* __restrict__ bq2,
    const float* __restrict__ Wq1, const float* __restrict__ Wq2,
    const float* __restrict__ W_z, const float* __restrict__ W_dec,
    const float* __restrict__ b_dec,
    const float* __restrict__ W_a, const float* __restrict__ b_a,
    const float* __restrict__ W_durd, const float* __restrict__ b_durd,
    const float* __restrict__ b_ih, const float* __restrict__ b_hh,
    const float* __restrict__ g_post, const float* __restrict__ g_prior,
    const unsigned int* __restrict__ ws, float* __restrict__ d_out)
{
    const int wv  = threadIdx.x >> 6;   // 0..3 : K-slice
    const int ln  = threadIdx.x & 63;   // output index
    const int row = blockIdx.x;

    __shared__ __align__(16) float s_in[128];    // [pa | pd]
    __shared__ __align__(16) float s_xh[128];    // [phix | h]
    __shared__ __align__(16) float s_h1[640];    // mix layer-1 outputs (10 comps)
    __shared__ __align__(16) float s_z[64];      // z = pm
    __shared__ __align__(16) float s_pz[64];     // phi_z
    __shared__ __align__(16) float s_part[256];  // [4][64] small partials
    __shared__ __align__(16) float s_p1[2560];   // [4][10][64] partials

    const uint4* Xp  = (const uint4*)(ws + OX);
    const uint4* P1p = (const uint4*)(ws + OP1);
    const uint4* Q1p = (const uint4*)(ws + OQ1);
    const uint4* P2p = (const uint4*)(ws + OP2);
    const uint4* Q2p = (const uint4*)(ws + OQ2);
    const uint4* Zp  = (const uint4*)(ws + OZ);
    const uint4* IHp = (const uint4*)(ws + OIH);
    const uint4* HHp = (const uint4*)(ws + OHH);

    const float bact = b_act[ln];
    const float wdur = W_dur[ln];
    const float bdur = b_dur[ln];
    const float bx   = b_x[ln];
    const float bz   = b_z[ln];

    float gpv[NZN], gqv[NZN];
#pragma unroll
    for (int n = 0; n < NZN; ++n) { gpv[n] = g_post[n]; gqv[n] = g_prior[n]; }

    float h     = 0.f;   // live in wave 0
    float klacc = 0.f;   // live in wave 0

    if (wv == 0) s_xh[64 + ln] = 0.f;   // h0

    for (int t = 0; t < TT; ++t) {
        // ---- ph0 (w0): input embed
        if (wv == 0) {
            const int   a  = acts[row * TT + t];
            const float du = durs[row * TT + t];
            s_in[ln]      = reluf(W_act[a * HD + ln] + bact);
            s_in[64 + ln] = reluf(du * wdur + bdur);
        }
        __syncthreads();  // B1

        // ---- ph1: phi_x partials (K=128, slice 32 per wave)
        {
            float2 ax[16];
#pragma unroll
            for (int u = 0; u < 16; ++u)
                ax[u] = *(const float2*)&s_in[32 * wv + 2 * u];
            float acc = 0.f;
#pragma unroll
            for (int j4 = 0; j4 < 4; ++j4) {
                uint4 wt = Xp[(4 * wv + j4) * 64 + ln];
                acc = bffma2(wt.x, ax[4 * j4 + 0], acc);
                acc = bffma2(wt.y, ax[4 * j4 + 1], acc);
                acc = bffma2(wt.z, ax[4 * j4 + 2], acc);
                acc = bffma2(wt.w, ax[4 * j4 + 3], acc);
            }
            s_part[wv * 64 + ln] = acc;
        }
        __syncthreads();  // B2

        // ---- ph2 (w0): phi_x reduce
        if (wv == 0) {
            s_xh[ln] = reluf(s_part[ln] + s_part[64 + ln] + s_part[128 + ln] +
                             s_part[192 + ln] + bx);
        }
        __syncthreads();  // B3

        // ---- ph3: mix layer-1 partials (post K=128, prior K=64)
        {
            float2 ap[16];
#pragma unroll
            for (int u = 0; u < 16; ++u)
                ap[u] = *(const float2*)&s_xh[32 * wv + 2 * u];
            float2 aq[8];
#pragma unroll
            for (int u = 0; u < 8; ++u)
                aq[u] = *(const float2*)&s_xh[64 + 16 * wv + 2 * u];
            float pn[NZN], qn[NZN];
#pragma unroll
            for (int n = 0; n < NZN; ++n) { pn[n] = 0.f; qn[n] = 0.f; }
#pragma unroll
            for (int n = 0; n < NZN; ++n) {
#pragma unroll
                for (int j4 = 0; j4 < 4; ++j4) {
                    uint4 wt = P1p[(n * 16 + 4 * wv + j4) * 64 + ln];
                    pn[n] = bffma2(wt.x, ap[4 * j4 + 0], pn[n]);
                    pn[n] = bffma2(wt.y, ap[4 * j4 + 1], pn[n]);
                    pn[n] = bffma2(wt.z, ap[4 * j4 + 2], pn[n]);
                    pn[n] = bffma2(wt.w, ap[4 * j4 + 3], pn[n]);
                }
#pragma unroll
                for (int j2 = 0; j2 < 2; ++j2) {
                    uint4 wt = Q1p[(n * 8 + 2 * wv + j2) * 64 + ln];
                    qn[n] = bffma2(wt.x, aq[4 * j2 + 0], qn[n]);
                    qn[n] = bffma2(wt.y, aq[4 * j2 + 1], qn[n]);
                    qn[n] = bffma2(wt.z, aq[4 * j2 + 2], qn[n]);
                    qn[n] = bffma2(wt.w, aq[4 * j2 + 3], qn[n]);
                }
            }
#pragma unroll
            for (int n = 0; n < NZN; ++n) {
                s_p1[(wv * 10 + n) * 64 + ln]       = pn[n];
                s_p1[(wv * 10 + 5 + n) * 64 + ln]   = qn[n];
            }
        }
        __syncthreads();  // B4

        // ---- ph4: mix layer-1 reduce (comp-split across waves)
        for (int c = wv; c < 10; c += 4) {
            float b = (c < 5) ? bp1[c * 64 + ln] : bq1[(c - 5) * 64 + ln];
            float v = b + s_p1[c * 64 + ln] + s_p1[(10 + c) * 64 + ln] +
                      s_p1[(20 + c) * 64 + ln] + s_p1[(30 + c) * 64 + ln];
            s_h1[c * 64 + ln] = reluf(v);
        }
        __syncthreads();  // B5

        // ---- ph5: mix layer-2 partials (10 comps, K=64 each)
        {
#pragma unroll
            for (int c = 0; c < 10; ++c) {
                float2 bb[8];
#pragma unroll
                for (int u = 0; u < 8; ++u)
                    bb[u] = *(const float2*)&s_h1[c * 64 + 16 * wv + 2 * u];
                float a = 0.f;
#pragma unroll
                for (int j2 = 0; j2 < 2; ++j2) {
                    uint4 wt = (c < 5) ? P2p[(c * 8 + 2 * wv + j2) * 64 + ln]
                                       : Q2p[((c - 5) * 8 + 2 * wv + j2) * 64 + ln];
                    a = bffma2(wt.x, bb[4 * j2 + 0], a);
                    a = bffma2(wt.y, bb[4 * j2 + 1], a);
                    a = bffma2(wt.z, bb[4 * j2 + 2], a);
                    a = bffma2(wt.w, bb[4 * j2 + 3], a);
                }
                s_p1[(wv * 10 + c) * 64 + ln] = a;
            }
        }
        __syncthreads();  // B6

        // ---- ph6 (w0): mix layer-2 reduce + gamma + KL + z
        if (wv == 0) {
            float pre[10];
#pragma unroll
            for (int c = 0; c < 10; ++c) {
                float b = (c < 5) ? bp2[c * 64 + ln] : bq2[(c - 5) * 64 + ln];
                pre[c] = b + s_p1[c * 64 + ln] + s_p1[(10 + c) * 64 + ln] +
                         s_p1[(20 + c) * 64 + ln] + s_p1[(30 + c) * 64 + ln];
            }
            float mpost = 0.f, mpri = 0.f;
#pragma unroll
            for (int n = 0; n < NZN; ++n) {
                mpost = fmaf(gpv[n], pre[n], mpost);
                mpri  = fmaf(gqv[n], pre[5 + n], mpri);
            }
            const float pm = reluf(mpost), ps = softplusf(mpost);
            const float qm = reluf(mpri),  qs = softplusf(mpri);
            const float dd = pm - qm;
            klacc += logf(qs / ps) + (ps * ps + dd * dd) / (2.f * qs * qs) - 0.5f;
            s_z[ln] = pm;   // z = pm (eps ~= 0)
        }
        __syncthreads();  // B7

        // ---- ph7: phi_z partials (K=64)
        {
            float2 az[8];
#pragma unroll
            for (int u = 0; u < 8; ++u)
                az[u] = *(const float2*)&s_z[16 * wv + 2 * u];
            float a = 0.f;
#pragma unroll
            for (int j2 = 0; j2 < 2; ++j2) {
                uint4 wt = Zp[(2 * wv + j2) * 64 + ln];
                a = bffma2(wt.x, az[4 * j2 + 0], a);
                a = bffma2(wt.y, az[4 * j2 + 1], a);
                a = bffma2(wt.z, az[4 * j2 + 2], a);
                a = bffma2(wt.w, az[4 * j2 + 3], a);
            }
            s_part[wv * 64 + ln] = a;
        }
        __syncthreads();  // B8

        // ---- ph8 (w0): phi_z reduce
        if (wv == 0) {
            s_pz[ln] = reluf(s_part[ln] + s_part[64 + ln] + s_part[128 + ln] +
                             s_part[192 + ln] + bz);
        }
        __syncthreads();  // B9

        // ---- ph9: GRU partials (gi K=128 over [phix|phiz], gh K=64 over h)
        {
            const float* xs = (wv < 2) ? (s_xh + 32 * wv) : (s_pz + 32 * (wv - 2));
            float2 ax[16];
#pragma unroll
            for (int u = 0; u < 16; ++u)
                ax[u] = *(const float2*)&xs[2 * u];
            float gi0 = 0.f, gi1 = 0.f, gi2 = 0.f;
#pragma unroll
            for (int j4 = 0; j4 < 4; ++j4) {
                const int j = 4 * wv + j4;
                uint4 w0t = IHp[(j * 3 + 0) * 64 + ln];
                uint4 w1t = IHp[(j * 3 + 1) * 64 + ln];
                uint4 w2t = IHp[(j * 3 + 2) * 64 + ln];
                gi0 = bffma2(w0t.x, ax[4 * j4 + 0], gi0);
                gi0 = bffma2(w0t.y, ax[4 * j4 + 1], gi0);
                gi0 = bffma2(w0t.z, ax[4 * j4 + 2], gi0);
                gi0 = bffma2(w0t.w, ax[4 * j4 + 3], gi0);
                gi1 = bffma2(w1t.x, ax[4 * j4 + 0], gi1);
                gi1 = bffma2(w1t.y, ax[4 * j4 + 1], gi1);
                gi1 = bffma2(w1t.z, ax[4 * j4 + 2], gi1);
                gi1 = bffma2(w1t.w, ax[4 * j4 + 3], gi1);
                gi2 = bffma2(w2t.x, ax[4 * j4 + 0], gi2);
                gi2 = bffma2(w2t.y, ax[4 * j4 + 1], gi2);
                gi2 = bffma2(w2t.z, ax[4 * j4 + 2], gi2);
                gi2 = bffma2(w2t.w, ax[4 * j4 + 3], gi2);
            }
            float2 ah[8];
#pragma unroll
            for (int u = 0; u < 8; ++u)
                ah[u] = *(const float2*)&s_xh[64 + 16 * wv + 2 * u];
            float gh0 = 0.f, gh1 = 0.f, gh2 = 0.f;
#pragma unroll
            for (int j2 = 0; j2 < 2; ++j2) {
                const int j = 2 * wv + j2;
                uint4 h0t = HHp[(j * 3 + 0) * 64 + ln];
                uint4 h1t = HHp[(j * 3 + 1) * 64 + ln];
                uint4 h2t = HHp[(j * 3 + 2) * 64 + ln];
                gh0 = bffma2(h0t.x, ah[4 * j2 + 0], gh0);
                gh0 = bffma2(h0t.y, ah[4 * j2 + 1], gh0);
                gh0 = bffma2(h0t.z, ah[4 * j2 + 2], gh0);
                gh0 = bffma2(h0t.w, ah[4 * j2 + 3], gh0);
                gh1 = bffma2(h1t.x, ah[4 * j2 + 0], gh1);
                gh1 = bffma2(h1t.y, ah[4 * j2 + 1], gh1);
                gh1 = bffma2(h1t.z, ah[4 * j2 + 2], gh1);
                gh1 = bffma2(h1t.w, ah[4 * j2 + 3], gh1);
                gh2 = bffma2(h2t.x, ah[4 * j2 + 0], gh2);
                gh2 = bffma2(h2t.y, ah[4 * j2 + 1], gh2);
                gh2 = bffma2(h2t.z, ah[4 * j2 + 2], gh2);
                gh2 = bffma2(h2t.w, ah[4 * j2 + 3], gh2);
            }
            s_p1[(wv * 10 + 0) * 64 + ln] = gi0;
            s_p1[(wv * 10 + 1) * 64 + ln] = gi1;
            s_p1[(wv * 10 + 2) * 64 + ln] = gi2;
            s_p1[(wv * 10 + 3) * 64 + ln] = gh0;
            s_p1[(wv * 10 + 4) * 64 + ln] = gh1;
            s_p1[(wv * 10 + 5) * 64 + ln] = gh2;
        }
        __syncthreads();  // B10

        // ---- ph10 (w0): GRU reduce + h update
        if (wv == 0) {
            float I0 = b_ih[ln], I1 = b_ih[64 + ln], I2 = b_ih[128 + ln];
            float G0 = b_hh[ln], G1 = b_hh[64 + ln], G2 = b_hh[128 + ln];
#pragma unroll
            for (int w = 0; w < 4; ++w) {
                I0 += s_p1[(w * 10 + 0) * 64 + ln];
                I1 += s_p1[(w * 10 + 1) * 64 + ln];
                I2 += s_p1[(w * 10 + 2) * 64 + ln];
                G0 += s_p1[(w * 10 + 3) * 64 + ln];
                G1 += s_p1[(w * 10 + 4) * 64 + ln];
                G2 += s_p1[(w * 10 + 5) * 64 + ln];
            }
            const float rr = sigmoidf_(I0 + G0);
            const float zz = sigmoidf_(I1 + G1);
            const float nn = tanhf(I2 + rr * G2);
            h = (1.f - zz) * nn + zz * h;
            s_xh[64 + ln] = h;
        }
        // no barrier here: B1 of next iter orders s_xh/s_in for all readers
    }

    // ================= final decode (wave 0 only, fp32 originals) ==========
    if (wv == 0) {
        // mix_prior(h)
        float r0 = bq1[ln], r1 = bq1[64 + ln], r2 = bq1[128 + ln];
        float r3 = bq1[192 + ln], r4 = bq1[256 + ln];
#pragma unroll 4
        for (int i = 0; i < 64; ++i) {
            const float v = s_xh[64 + i];
            r0 += v * Wq1[(0 * 64 + i) * HD + ln];
            r1 += v * Wq1[(1 * 64 + i) * HD + ln];
            r2 += v * Wq1[(2 * 64 + i) * HD + ln];
            r3 += v * Wq1[(3 * 64 + i) * HD + ln];
            r4 += v * Wq1[(4 * 64 + i) * HD + ln];
        }
        s_h1[0 * 64 + ln] = reluf(r0);
        s_h1[1 * 64 + ln] = reluf(r1);
        s_h1[2 * 64 + ln] = reluf(r2);
        s_h1[3 * 64 + ln] = reluf(r3);
        s_h1[4 * 64 + ln] = reluf(r4);
        float u0 = bq2[ln], u1 = bq2[64 + ln], u2 = bq2[128 + ln];
        float u3 = bq2[192 + ln], u4 = bq2[256 + ln];
#pragma unroll 4
        for (int o = 0; o < 64; ++o) {
            u0 += s_h1[0 * 64 + o] * Wq2[(0 * 64 + o) * HD + ln];
            u1 += s_h1[1 * 64 + o] * Wq2[(1 * 64 + o) * HD + ln];
            u2 += s_h1[2 * 64 + o] * Wq2[(2 * 64 + o) * HD + ln];
            u3 += s_h1[3 * 64 + o] * Wq2[(3 * 64 + o) * HD + ln];
            u4 += s_h1[4 * 64 + o] * Wq2[(4 * 64 + o) * HD + ln];
        }
        const float mpri = gqv[0] * u0 + gqv[1] * u1 + gqv[2] * u2 +
                           gqv[3] * u3 + gqv[4] * u4;
        const float z = reluf(mpri);   // z = qm + qs*eps, eps ~= 0
        s_z[ln] = z;
        float zacc = bz;
#pragma unroll 8
        for (int i = 0; i < 64; ++i) zacc += s_z[i] * W_z[i * HD + ln];
        const float phiz = reluf(zacc);
        s_pz[ln] = phiz;
        float d = b_dec[ln];
#pragma unroll 8
        for (int i = 0; i < 64; ++i) {
            d += s_pz[i]       * W_dec[i * HD + ln];
            d += s_xh[64 + i]  * W_dec[(64 + i) * HD + ln];
        }
        const float dec = reluf(d);
        s_part[ln] = dec;
        float lg = 0.f;
        if (ln < ADIM) {
            lg = b_a[ln];
#pragma unroll 8
            for (int o = 0; o < 64; ++o) lg += s_part[o] * W_a[o * ADIM + ln];
            d_out[row * ADIM + ln] = lg;    // output 0
            s_z[ln] = lg;                   // reuse for broadcast
        }
        float pl = bact;
#pragma unroll
        for (int j = 0; j < ADIM; ++j) pl += s_z[j] * W_act[j * HD + ln];
        pl = reluf(pl);
        float contrib = pl * W_durd[ln] + dec * W_durd[64 + ln];
        contrib = wave_sum64(contrib);
        const float kls = wave_sum64(klacc);
        if (ln == 0) {
            const float ddv = contrib + b_durd[0];
            d_out[20480 + row] = ddv;               // output 1
            d_out[21504 + row] = softplusf(ddv);    // output 2
            atomicAdd(d_out + 22528, kls * (1.f / 1024.f));  // output 3
        }
    }
}

extern "C" void kernel_launch(void* const* d_in, const int* in_sizes, int n_in,
                              void* d_out, int out_size, void* d_ws, size_t ws_size,
                              hipStream_t stream)
{
    const int*   acts    = (const int*)  d_in[0];
    const float* durs    = (const float*)d_in[1];
    const float* W_act   = (const float*)d_in[2];
    const float* b_act   = (const float*)d_in[3];
    const float* W_dur   = (const float*)d_in[4];
    const float* b_dur   = (const float*)d_in[5];
    const float* W_x     = (const float*)d_in[6];
    const float* b_x     = (const float*)d_in[7];
    const float* W_z     = (const float*)d_in[8];
    const float* b_z     = (const float*)d_in[9];
    const float* Wp1     = (const float*)d_in[10];
    const float* bp1     = (const float*)d_in[11];
    const float* Wp2     = (const float*)d_in[12];
    const float* bp2     = (const float*)d_in[13];
    const float* Wq1     = (const float*)d_in[14];
    const float* bq1     = (const float*)d_in[15];
    const float* Wq2     = (const float*)d_in[16];
    const float* bq2     = (const float*)d_in[17];
    const float* W_dec   = (const float*)d_in[18];
    const float* b_dec   = (const float*)d_in[19];
    const float* W_a     = (const float*)d_in[20];
    const float* b_a     = (const float*)d_in[21];
    const float* W_durd  = (const float*)d_in[22];
    const float* b_durd  = (const float*)d_in[23];
    const float* W_ih    = (const float*)d_in[24];
    const float* W_hh    = (const float*)d_in[25];
    const float* b_ih    = (const float*)d_in[26];
    const float* b_hh    = (const float*)d_in[27];
    const float* g_post  = (const float*)d_in[28];
    const float* g_prior = (const float*)d_in[29];
    float* out = (float*)d_out;
    unsigned int* ws = (unsigned int*)d_ws;

    vrnn_zero<<<1, 1, 0, stream>>>(out);
    vrnn_pack<<<128, 256, 0, stream>>>(W_x, Wp1, Wq1, Wp2, Wq2, W_z, W_ih, W_hh, ws);
    vrnn_main<<<1024, 256, 0, stream>>>(
        acts, durs, W_act, b_act, W_dur, b_dur, b_x, b_z,
        bp1, bq1, bp2, bq2, Wq1, Wq2, W_z, W_dec, b_dec,
        W_a, b_a, W_durd, b_durd, b_ih, b_hh, g_post, g_prior,
        ws, out);
}

// Round 4
// 959.999 us; speedup vs baseline: 29.6408x; 29.6408x over previous
//
#include <hip/hip_runtime.h>
#include <hip/hip_bf16.h>
#include <math.h>

// R4: MFMA formulation. 64 blocks x 16 rows; 4 waves/block each owning a
// 16-wide N-slice of every matvec. Weights pre-packed (bf16) into per-wave
// fragment streams in d_ws (74 frags/wave/step, consumption order).
// Activations staged in XOR-swizzled LDS bf16 buffers; h kept in f32 regs.
// eps ~= 0 approximation unchanged (passed R1-R3).

#define TT   128
#define NZN  5
#define ADIM 20
#define ROWS 16
#define FR   74

typedef __attribute__((ext_vector_type(8))) short short8;
typedef __attribute__((ext_vector_type(4))) float f32x4;

__device__ __forceinline__ float reluf(float x) { return fmaxf(x, 0.f); }
__device__ __forceinline__ float softplusf(float x) {
    return fmaxf(x, 0.f) + log1pf(expf(-fabsf(x)));
}
__device__ __forceinline__ float sigmoidf_(float x) { return 1.f / (1.f + expf(-x)); }
__device__ __forceinline__ unsigned short f2bf(float x) {
    union { float f; unsigned int u; } v; v.f = x;
    unsigned int r = v.u + 0x7fffu + ((v.u >> 16) & 1u);   // RTNE
    return (unsigned short)(r >> 16);
}
__device__ __forceinline__ float wave_sum64(float v) {
#pragma unroll
    for (int off = 32; off > 0; off >>= 1) v += __shfl_xor(v, off, 64);
    return v;
}
// swizzled A-fragment loads: row c, 8 contiguous logical cols starting col0
__device__ __forceinline__ short8 lda64(const short* b, int c, int col0) {
    return *(const short8*)(b + c * 64 + (col0 ^ ((c & 7) << 3)));
}
__device__ __forceinline__ short8 lda128(const short* b, int c, int col0) {
    return *(const short8*)(b + c * 128 + (col0 ^ ((c & 7) << 3)));
}
#define MFMA(a, b, acc) __builtin_amdgcn_mfma_f32_16x16x32_bf16((a), (b), (acc), 0, 0, 0)

__global__ void vrnn_zero(float* out) { out[22528] = 0.f; }

// ---- pack: ws frag (w, f, lane) -> short8 of B[k = 32*kt + 8*g + j][ncol]
__global__ __launch_bounds__(256) void vrnn_pack(
    const float* __restrict__ W_x,  const float* __restrict__ Wp1,
    const float* __restrict__ Wq1,  const float* __restrict__ Wp2,
    const float* __restrict__ Wq2,  const float* __restrict__ W_z,
    const float* __restrict__ W_ih, const float* __restrict__ W_hh,
    short* __restrict__ ws)
{
    const int tid = blockIdx.x * blockDim.x + threadIdx.x;   // 74*256 = 18944
    const int l = tid & 63, f = (tid >> 6) % FR, w = (tid >> 6) / FR;
    if (w >= 4) return;
    const int g = l >> 4, c = l & 15;
    const int kb = 8 * g;
    const float* src; int ld, ncol, k0;
    if (f < 4)       { src = W_x;                      ld = 64;  ncol = 16 * w + c; k0 = 32 * f; }
    else if (f < 24) { int r = f - 4;  int net = r >> 2, kt = r & 3;
                       src = Wp1 + net * 128 * 64;     ld = 64;  ncol = 16 * w + c; k0 = 32 * kt; }
    else if (f < 34) { int r = f - 24; int net = r >> 1, kt = r & 1;
                       src = Wq1 + net * 64 * 64;      ld = 64;  ncol = 16 * w + c; k0 = 32 * kt; }
    else if (f < 44) { int r = f - 34; int net = r >> 1, kt = r & 1;
                       src = Wp2 + net * 64 * 64;      ld = 64;  ncol = 16 * w + c; k0 = 32 * kt; }
    else if (f < 54) { int r = f - 44; int net = r >> 1, kt = r & 1;
                       src = Wq2 + net * 64 * 64;      ld = 64;  ncol = 16 * w + c; k0 = 32 * kt; }
    else if (f < 56) { src = W_z;                      ld = 64;  ncol = 16 * w + c; k0 = 32 * (f - 54); }
    else if (f < 68) { int r = f - 56; int gate = r >> 2, kt = r & 3;
                       src = W_ih;                     ld = 192; ncol = gate * 64 + 16 * w + c; k0 = 32 * kt; }
    else             { int r = f - 68; int gate = r >> 1, kt = r & 1;
                       src = W_hh;                     ld = 192; ncol = gate * 64 + 16 * w + c; k0 = 32 * kt; }
    short8 frag;
#pragma unroll
    for (int j = 0; j < 8; ++j)
        frag[j] = (short)f2bf(src[(k0 + kb + j) * ld + ncol]);
    *(short8*)(ws + ((w * FR + f) * 64 + l) * 8) = frag;
}

__global__ __launch_bounds__(256) void vrnn_main(
    const int* __restrict__ acts, const float* __restrict__ durs,
    const float* __restrict__ W_act, const float* __restrict__ b_act,
    const float* __restrict__ W_dur, const float* __restrict__ b_dur,
    const float* __restrict__ b_x, const float* __restrict__ b_z,
    const float* __restrict__ bp1, const float* __restrict__ bp2,
    const float* __restrict__ bq1, const float* __restrict__ bq2,
    const float* __restrict__ b_ih, const float* __restrict__ b_hh,
    const float* __restrict__ g_post, const float* __restrict__ g_prior,
    const float* __restrict__ Wq1, const float* __restrict__ Wq2,
    const float* __restrict__ W_z, const float* __restrict__ W_dec,
    const float* __restrict__ b_dec, const float* __restrict__ W_a,
    const float* __restrict__ b_a, const float* __restrict__ W_durd,
    const float* __restrict__ b_durd,
    const short* __restrict__ ws, float* __restrict__ d_out)
{
    const int w = threadIdx.x >> 6, l = threadIdx.x & 63;
    const int g = l >> 4, c = l & 15;
    const int row0 = blockIdx.x * ROWS;
    const int fc = 16 * w + c;          // this wave-lane's output feature col

    __shared__ __align__(16) short s_xz[ROWS * 128];      // [phi_x | phi_z]
    __shared__ __align__(16) short s_h[ROWS * 64];        // h (bf16)
    __shared__ __align__(16) short s_h1p[NZN][ROWS * 64];
    __shared__ __align__(16) short s_h1q[NZN][ROWS * 64];
    __shared__ __align__(16) short s_z[ROWS * 64];
    __shared__ float s_klsum[ROWS];
    __shared__ float s_hf[ROWS * 64];
    __shared__ float s_fin[4][320];

    const short8* Bw = ((const short8*)ws) + (w * FR) * 64 + l;

    // bias / gamma preloads (feature-slice fc)
    const float bxr = b_x[fc], bzr = b_z[fc];
    float bp1r[NZN], bq1r[NZN], bp2r[NZN], bq2r[NZN], gp[NZN], gq[NZN];
#pragma unroll
    for (int n = 0; n < NZN; ++n) {
        bp1r[n] = bp1[n * 64 + fc]; bq1r[n] = bq1[n * 64 + fc];
        bp2r[n] = bp2[n * 64 + fc]; bq2r[n] = bq2[n * 64 + fc];
        gp[n] = g_post[n]; gq[n] = g_prior[n];
    }
    float bihr[3], bhhr[3];
#pragma unroll
    for (int gg = 0; gg < 3; ++gg) { bihr[gg] = b_ih[gg * 64 + fc]; bhhr[gg] = b_hh[gg * 64 + fc]; }

    float h0r = 0.f, h1r = 0.f, h2r = 0.f, h3r = 0.f;           // h, rows 4g+0..3
    float kl0 = 0.f, kl1 = 0.f, kl2 = 0.f, kl3 = 0.f;           // KL partials

    for (int i = threadIdx.x; i < ROWS * 64; i += 256) s_h[i] = 0;
    if (threadIdx.x < ROWS) s_klsum[threadIdx.x] = 0.f;

    for (int t = 0; t < TT; ++t) {
        __syncthreads();                                        // BAR top
        // ---- P1: input embed (A in-reg) + W_x MFMA -> phi_x
        const int   arow = acts[(row0 + c) * TT + t];
        const float dur  = durs[(row0 + c) * TT + t];
        short8 a0, a1, a2, a3;
        {
            const float* wa = W_act + arow * 64 + 8 * g;
            const float* ba = b_act + 8 * g;
            const float* wd = W_dur + 8 * g;
            const float* bd = b_dur + 8 * g;
#pragma unroll
            for (int j = 0; j < 8; ++j) {
                a0[j] = (short)f2bf(reluf(wa[j]      + ba[j]));
                a1[j] = (short)f2bf(reluf(wa[32 + j] + ba[32 + j]));
                a2[j] = (short)f2bf(reluf(dur * wd[j]      + bd[j]));
                a3[j] = (short)f2bf(reluf(dur * wd[32 + j] + bd[32 + j]));
            }
        }
        {
            f32x4 x = {0.f, 0.f, 0.f, 0.f};
            x = MFMA(a0, Bw[0 * 64], x); x = MFMA(a1, Bw[1 * 64], x);
            x = MFMA(a2, Bw[2 * 64], x); x = MFMA(a3, Bw[3 * 64], x);
#pragma unroll
            for (int r = 0; r < 4; ++r) {
                const int rw = 4 * g + r;
                s_xz[rw * 128 + (fc ^ ((rw & 7) << 3))] = (short)f2bf(reluf(x[r] + bxr));
            }
        }
        __syncthreads();                                        // BAR1
        // ---- P2: mix layer-1 (post K=128, prior K=64)
        short8 ax0 = lda128(s_xz, c, 8 * g);
        short8 ax1 = lda128(s_xz, c, 32 + 8 * g);
        short8 ah0 = lda64(s_h, c, 8 * g);
        short8 ah1 = lda64(s_h, c, 32 + 8 * g);
#pragma unroll
        for (int net = 0; net < NZN; ++net) {
            f32x4 p = {0.f, 0.f, 0.f, 0.f}, q = {0.f, 0.f, 0.f, 0.f};
            p = MFMA(ax0, Bw[(4 + net * 4 + 0) * 64], p);
            p = MFMA(ax1, Bw[(4 + net * 4 + 1) * 64], p);
            p = MFMA(ah0, Bw[(4 + net * 4 + 2) * 64], p);
            p = MFMA(ah1, Bw[(4 + net * 4 + 3) * 64], p);
            q = MFMA(ah0, Bw[(24 + net * 2 + 0) * 64], q);
            q = MFMA(ah1, Bw[(24 + net * 2 + 1) * 64], q);
#pragma unroll
            for (int r = 0; r < 4; ++r) {
                const int rw = 4 * g + r;
                const int si = rw * 64 + (fc ^ ((rw & 7) << 3));
                s_h1p[net][si] = (short)f2bf(reluf(p[r] + bp1r[net]));
                s_h1q[net][si] = (short)f2bf(reluf(q[r] + bq1r[net]));
            }
        }
        __syncthreads();                                        // BAR2
        // ---- P3: mix layer-2 + gamma + KL + z
        {
            float mp0 = 0.f, mp1 = 0.f, mp2 = 0.f, mp3 = 0.f;
            float mq0 = 0.f, mq1 = 0.f, mq2 = 0.f, mq3 = 0.f;
#pragma unroll
            for (int net = 0; net < NZN; ++net) {
                short8 hp0 = lda64(s_h1p[net], c, 8 * g);
                short8 hp1 = lda64(s_h1p[net], c, 32 + 8 * g);
                short8 hq0 = lda64(s_h1q[net], c, 8 * g);
                short8 hq1 = lda64(s_h1q[net], c, 32 + 8 * g);
                f32x4 p = {0.f, 0.f, 0.f, 0.f}, q = {0.f, 0.f, 0.f, 0.f};
                p = MFMA(hp0, Bw[(34 + net * 2 + 0) * 64], p);
                p = MFMA(hp1, Bw[(34 + net * 2 + 1) * 64], p);
                q = MFMA(hq0, Bw[(44 + net * 2 + 0) * 64], q);
                q = MFMA(hq1, Bw[(44 + net * 2 + 1) * 64], q);
                mp0 = fmaf(gp[net], p[0] + bp2r[net], mp0);
                mp1 = fmaf(gp[net], p[1] + bp2r[net], mp1);
                mp2 = fmaf(gp[net], p[2] + bp2r[net], mp2);
                mp3 = fmaf(gp[net], p[3] + bp2r[net], mp3);
                mq0 = fmaf(gq[net], q[0] + bq2r[net], mq0);
                mq1 = fmaf(gq[net], q[1] + bq2r[net], mq1);
                mq2 = fmaf(gq[net], q[2] + bq2r[net], mq2);
                mq3 = fmaf(gq[net], q[3] + bq2r[net], mq3);
            }
#pragma unroll
            for (int r = 0; r < 4; ++r) {
                const float mpv = (r == 0) ? mp0 : (r == 1) ? mp1 : (r == 2) ? mp2 : mp3;
                const float mqv = (r == 0) ? mq0 : (r == 1) ? mq1 : (r == 2) ? mq2 : mq3;
                const float pm = reluf(mpv), ps = softplusf(mpv);
                const float qm = reluf(mqv), qs = softplusf(mqv);
                const float dd = pm - qm;
                const float term = logf(qs / ps) + (ps * ps + dd * dd) / (2.f * qs * qs) - 0.5f;
                if (r == 0) kl0 += term; else if (r == 1) kl1 += term;
                else if (r == 2) kl2 += term; else kl3 += term;
                const int rw = 4 * g + r;
                s_z[rw * 64 + (fc ^ ((rw & 7) << 3))] = (short)f2bf(pm);
            }
        }
        __syncthreads();                                        // BAR3
        // ---- P4: phi_z
        {
            short8 az0 = lda64(s_z, c, 8 * g);
            short8 az1 = lda64(s_z, c, 32 + 8 * g);
            f32x4 zz = {0.f, 0.f, 0.f, 0.f};
            zz = MFMA(az0, Bw[54 * 64], zz);
            zz = MFMA(az1, Bw[55 * 64], zz);
#pragma unroll
            for (int r = 0; r < 4; ++r) {
                const int rw = 4 * g + r;
                s_xz[rw * 128 + ((64 + fc) ^ ((rw & 7) << 3))] = (short)f2bf(reluf(zz[r] + bzr));
            }
        }
        __syncthreads();                                        // BAR4
        // ---- P5: GRU (x = [phi_x|phi_z] K=128, h K=64)
        {
            short8 gx2 = lda128(s_xz, c, 64 + 8 * g);
            short8 gx3 = lda128(s_xz, c, 96 + 8 * g);
            f32x4 gi0 = {0.f,0.f,0.f,0.f}, gi1 = {0.f,0.f,0.f,0.f}, gi2 = {0.f,0.f,0.f,0.f};
            f32x4 gh0 = {0.f,0.f,0.f,0.f}, gh1 = {0.f,0.f,0.f,0.f}, gh2 = {0.f,0.f,0.f,0.f};
            gi0 = MFMA(ax0, Bw[(56 + 0) * 64], gi0); gi0 = MFMA(ax1, Bw[(56 + 1) * 64], gi0);
            gi0 = MFMA(gx2, Bw[(56 + 2) * 64], gi0); gi0 = MFMA(gx3, Bw[(56 + 3) * 64], gi0);
            gi1 = MFMA(ax0, Bw[(60 + 0) * 64], gi1); gi1 = MFMA(ax1, Bw[(60 + 1) * 64], gi1);
            gi1 = MFMA(gx2, Bw[(60 + 2) * 64], gi1); gi1 = MFMA(gx3, Bw[(60 + 3) * 64], gi1);
            gi2 = MFMA(ax0, Bw[(64 + 0) * 64], gi2); gi2 = MFMA(ax1, Bw[(64 + 1) * 64], gi2);
            gi2 = MFMA(gx2, Bw[(64 + 2) * 64], gi2); gi2 = MFMA(gx3, Bw[(64 + 3) * 64], gi2);
            gh0 = MFMA(ah0, Bw[(68 + 0) * 64], gh0); gh0 = MFMA(ah1, Bw[(68 + 1) * 64], gh0);
            gh1 = MFMA(ah0, Bw[(70 + 0) * 64], gh1); gh1 = MFMA(ah1, Bw[(70 + 1) * 64], gh1);
            gh2 = MFMA(ah0, Bw[(72 + 0) * 64], gh2); gh2 = MFMA(ah1, Bw[(72 + 1) * 64], gh2);
#pragma unroll
            for (int r = 0; r < 4; ++r) {
                const float rr  = sigmoidf_(gi0[r] + bihr[0] + gh0[r] + bhhr[0]);
                const float zg  = sigmoidf_(gi1[r] + bihr[1] + gh1[r] + bhhr[1]);
                const float nn  = tanhf(gi2[r] + bihr[2] + rr * (gh2[r] + bhhr[2]));
                float* hp = (r == 0) ? &h0r : (r == 1) ? &h1r : (r == 2) ? &h2r : &h3r;
                *hp = (1.f - zg) * nn + zg * (*hp);
            }
        }
        __syncthreads();                                        // BAR5 (s_h reads done)
        // ---- P6: stage h
#pragma unroll
        for (int r = 0; r < 4; ++r) {
            const int rw = 4 * g + r;
            const float hv = (r == 0) ? h0r : (r == 1) ? h1r : (r == 2) ? h2r : h3r;
            s_h[rw * 64 + (fc ^ ((rw & 7) << 3))] = (short)f2bf(hv);
        }
    }

    // ================= epilogue =================
#pragma unroll
    for (int r = 0; r < 4; ++r) {
        const float hv = (r == 0) ? h0r : (r == 1) ? h1r : (r == 2) ? h2r : h3r;
        s_hf[(4 * g + r) * 64 + fc] = hv;
    }
    // KL reduce over c (lanes 0..15 within group)
    {
        float k0v = kl0, k1v = kl1, k2v = kl2, k3v = kl3;
#pragma unroll
        for (int off = 1; off < 16; off <<= 1) {
            k0v += __shfl_xor(k0v, off, 64); k1v += __shfl_xor(k1v, off, 64);
            k2v += __shfl_xor(k2v, off, 64); k3v += __shfl_xor(k3v, off, 64);
        }
        if (c == 0) {
            atomicAdd(&s_klsum[4 * g + 0], k0v);
            atomicAdd(&s_klsum[4 * g + 1], k1v);
            atomicAdd(&s_klsum[4 * g + 2], k2v);
            atomicAdd(&s_klsum[4 * g + 3], k3v);
        }
    }
    __syncthreads();

    // final decode: wave w handles local rows 4w..4w+3 (fp32 original weights)
    {
        float* sf = s_fin[w];
        for (int rr = 0; rr < 4; ++rr) {
            const int lr = w * 4 + rr, grow = row0 + lr;
            float accn[NZN];
#pragma unroll
            for (int n = 0; n < NZN; ++n) accn[n] = bq1[n * 64 + l];
            for (int i = 0; i < 64; ++i) {
                const float hv = s_hf[lr * 64 + i];
#pragma unroll
                for (int n = 0; n < NZN; ++n) accn[n] += hv * Wq1[(n * 64 + i) * 64 + l];
            }
#pragma unroll
            for (int n = 0; n < NZN; ++n) sf[n * 64 + l] = reluf(accn[n]);
            float u[NZN];
#pragma unroll
            for (int n = 0; n < NZN; ++n) u[n] = bq2[n * 64 + l];
            for (int o = 0; o < 64; ++o) {
#pragma unroll
                for (int n = 0; n < NZN; ++n) u[n] += sf[n * 64 + o] * Wq2[(n * 64 + o) * 64 + l];
            }
            float mpri = 0.f;
#pragma unroll
            for (int n = 0; n < NZN; ++n) mpri = fmaf(gq[n], u[n], mpri);
            sf[l] = reluf(mpri);                      // z (net0 consumed)
            float za = b_z[l];
            for (int i = 0; i < 64; ++i) za += sf[i] * W_z[i * 64 + l];
            sf[64 + l] = reluf(za);                   // phi_z (net1 consumed)
            float dv = b_dec[l];
            for (int i = 0; i < 64; ++i) {
                dv += sf[64 + i] * W_dec[i * 64 + l];
                dv += s_hf[lr * 64 + i] * W_dec[(64 + i) * 64 + l];
            }
            const float dec = reluf(dv);
            sf[128 + l] = dec;
            float lg = 0.f;
            if (l < ADIM) {
                lg = b_a[l];
                for (int o = 0; o < 64; ++o) lg += sf[128 + o] * W_a[o * ADIM + l];
                d_out[grow * ADIM + l] = lg;          // output 0
                sf[192 + l] = lg;
            }
            float pl = b_act[l];
#pragma unroll
            for (int j = 0; j < ADIM; ++j) pl += sf[192 + j] * W_act[j * 64 + l];
            pl = reluf(pl);
            float contrib = pl * W_durd[l] + dec * W_durd[64 + l];
            contrib = wave_sum64(contrib);
            if (l == 0) {
                const float dd = contrib + b_durd[0];
                d_out[20480 + grow] = dd;             // output 1
                d_out[21504 + grow] = softplusf(dd);  // output 2
            }
        }
    }
    if (threadIdx.x == 0) {
        float s = 0.f;
#pragma unroll
        for (int i = 0; i < ROWS; ++i) s += s_klsum[i];
        atomicAdd(d_out + 22528, s * (1.f / 1024.f)); // output 3
    }
}

extern "C" void kernel_launch(void* const* d_in, const int* in_sizes, int n_in,
                              void* d_out, int out_size, void* d_ws, size_t ws_size,
                              hipStream_t stream)
{
    const int*   acts    = (const int*)  d_in[0];
    const float* durs    = (const float*)d_in[1];
    const float* W_act   = (const float*)d_in[2];
    const float* b_act   = (const float*)d_in[3];
    const float* W_dur   = (const float*)d_in[4];
    const float* b_dur   = (const float*)d_in[5];
    const float* W_x     = (const float*)d_in[6];
    const float* b_x     = (const float*)d_in[7];
    const float* W_z     = (const float*)d_in[8];
    const float* b_z     = (const float*)d_in[9];
    const float* Wp1     = (const float*)d_in[10];
    const float* bp1     = (const float*)d_in[11];
    const float* Wp2     = (const float*)d_in[12];
    const float* bp2     = (const float*)d_in[13];
    const float* Wq1     = (const float*)d_in[14];
    const float* bq1     = (const float*)d_in[15];
    const float* Wq2     = (const float*)d_in[16];
    const float* bq2     = (const float*)d_in[17];
    const float* W_dec   = (const float*)d_in[18];
    const float* b_dec   = (const float*)d_in[19];
    const float* W_a     = (const float*)d_in[20];
    const float* b_a     = (const float*)d_in[21];
    const float* W_durd  = (const float*)d_in[22];
    const float* b_durd  = (const float*)d_in[23];
    const float* W_ih    = (const float*)d_in[24];
    const float* W_hh    = (const float*)d_in[25];
    const float* b_ih    = (const float*)d_in[26];
    const float* b_hh    = (const float*)d_in[27];
    const float* g_post  = (const float*)d_in[28];
    const float* g_prior = (const float*)d_in[29];
    float* out = (float*)d_out;
    short* ws  = (short*)d_ws;

    vrnn_zero<<<1, 1, 0, stream>>>(out);
    vrnn_pack<<<74, 256, 0, stream>>>(W_x, Wp1, Wq1, Wp2, Wq2, W_z, W_ih, W_hh, ws);
    vrnn_main<<<64, 256, 0, stream>>>(
        acts, durs, W_act, b_act, W_dur, b_dur, b_x, b_z,
        bp1, bp2, bq1, bq2, b_ih, b_hh, g_post, g_prior,
        Wq1, Wq2, W_z, W_dec, b_dec, W_a, b_a, W_durd, b_durd,
        ws, out);
}